// Round 6
// baseline (56.406 us; speedup 1.0000x reference)
//
#include <hip/hip_runtime.h>

#define KC   21      // num classes
#define BB   8       // batch
#define CC   256     // feat channels
#define HWP  65536   // 256*256 output pixels per image
#define SRC  4096    // 64*64 source pixels
#define NS   64      // p-chunks of 64
#define PC   64      // p per chunk
#define FST  257     // fs row stride: bank=(p+c)%32 -> 2-way (free)

// d_ws float layout: counts[256] | Wmap[B][K][SRC] | partial[B][NS][K][C]
#define WS_COUNTS 0
#define WS_WMAP   256
#define WS_PART   (256 + BB*KC*SRC)          // 688384
#define WS_ZERO   (256 + BB*KC*SRC)          // zero counts+Wmap (688384 floats)

__global__ __launch_bounds__(256)
void p0_zero(float* ws) {
    int i = blockIdx.x * 256 + threadIdx.x;
    if (i < WS_ZERO / 4)
        *reinterpret_cast<float4*>(ws + i * 4) = make_float4(0.f, 0.f, 0.f, 0.f);
}

// ---- Phase 1: argmax + gt-match -> bilinear-weight scatter + exact counts ----
__global__ __launch_bounds__(256)
void p1_classify_scatter(const float* __restrict__ preds,
                         const int*   __restrict__ masks,
                         float* __restrict__ Wmap,     // [B][K][SRC]
                         float* __restrict__ counts)   // [B][K]
{
    __shared__ float hist[KC];
    int tid = threadIdx.x;
    if (tid < KC) hist[tid] = 0.f;
    __syncthreads();

    int idx = blockIdx.x * 256 + tid;            // over B*HWP/4 = 131072
    int b   = idx >> 14;                         // block-uniform (64 blocks / image)
    int hw4 = (idx & 16383) << 2;

    const float* pb = preds + (size_t)b * KC * HWP + hw4;
    float4 v[KC];
#pragma unroll
    for (int k = 0; k < KC; ++k)
        v[k] = *reinterpret_cast<const float4*>(pb + (size_t)k * HWP);

    int4 mm = *reinterpret_cast<const int4*>(masks + b * HWP + hw4);

    float bx = v[0].x, by = v[0].y, bz = v[0].z, bw = v[0].w;
    int   ix = 0, iy = 0, iz = 0, iw = 0;
#pragma unroll
    for (int k = 1; k < KC; ++k) {
        if (v[k].x > bx) { bx = v[k].x; ix = k; }
        if (v[k].y > by) { by = v[k].y; iy = k; }
        if (v[k].z > bz) { bz = v[k].z; iz = k; }
        if (v[k].w > bw) { bw = v[k].w; iw = k; }
    }

    int m[4]  = { mm.x, mm.y, mm.z, mm.w };
    int am[4] = { ix, iy, iz, iw };
#pragma unroll
    for (int j = 0; j < 4; ++j) {
        int mv = m[j];
        if (mv == am[j] && (unsigned)mv < KC) {
            int hw = hw4 + j;
            int h = hw >> 8, w = hw & 255;
            float sy = h * 0.25f - 0.375f;       // half-pixel bilinear at 4x
            float sx = w * 0.25f - 0.375f;
            int y0 = (int)floorf(sy), x0 = (int)floorf(sx);
            float wy = sy - (float)y0, wx = sx - (float)x0;
            int y0c = y0 < 0 ? 0 : y0;
            int y1c = y0 + 1 > 63 ? 63 : y0 + 1;
            int x0c = x0 < 0 ? 0 : x0;
            int x1c = x0 + 1 > 63 ? 63 : x0 + 1;
            float* Wb = Wmap + (size_t)(b * KC + mv) * SRC;
            atomicAdd(&Wb[y0c * 64 + x0c], (1.f - wy) * (1.f - wx));
            atomicAdd(&Wb[y0c * 64 + x1c], (1.f - wy) * wx);
            atomicAdd(&Wb[y1c * 64 + x0c], wy * (1.f - wx));
            atomicAdd(&Wb[y1c * 64 + x1c], wy * wx);
            atomicAdd(&hist[mv], 1.0f);          // integer-valued -> order-exact
        }
    }
    __syncthreads();
    if (tid < KC && hist[tid] != 0.f)
        atomicAdd(&counts[b * KC + tid], hist[tid]);
}

// ---- Phase 2: partial[b,s,k,c] = sum_{p in chunk s} feats[b,c,p] * W[b,k,p] --
// grid (64 s, 8 b) x 256 threads (thread = channel c). 65.8 KB LDS -> 2
// blocks/CU, 2 waves/SIMD. No atomics, no LDS W: W read via wave-UNIFORM
// global loads (scalarizes; L2-hot). feats staged p-major, pulled to f[64].
__global__ __launch_bounds__(256, 2)
void p2_contract(const float* __restrict__ feats,   // [B][C][SRC]
                 const float* __restrict__ Wmap,    // [B][K][SRC]
                 float* __restrict__ partial)       // [B][NS][K][C]
{
    __shared__ float fs[PC * FST];    // [64 p][257] = 65.8 KB
    int s = blockIdx.x, b = blockIdx.y;
    int tid = threadIdx.x;
    int p0 = s * PC;

    // stage feats[256 c][64 p] transposed -> fs[p][c]; 16 float4/thread
    {
        int q = tid & 15, c0 = tid >> 4;          // q: p-group, c0: row base
#pragma unroll
        for (int i = 0; i < 16; ++i) {
            int c = i * 16 + c0;
            float4 f4 = *reinterpret_cast<const float4*>(
                feats + (size_t)(b * CC + c) * SRC + p0 + q * 4);
            fs[(q * 4 + 0) * FST + c] = f4.x;     // bank=(p+c)%32 -> 2-way free
            fs[(q * 4 + 1) * FST + c] = f4.y;
            fs[(q * 4 + 2) * FST + c] = f4.z;
            fs[(q * 4 + 3) * FST + c] = f4.w;
        }
    }
    __syncthreads();

    // pull own channel column into registers (64 b32, 2-way banks)
    float f[PC];
#pragma unroll
    for (int p = 0; p < PC; ++p) f[p] = fs[p * FST + tid];

    const float* wb = Wmap + (size_t)b * KC * SRC + p0;
    float* op = partial + (((size_t)(b * NS + s)) * KC) * CC + tid;

#pragma unroll 1
    for (int k = 0; k < KC; ++k) {
        const float4* wk = reinterpret_cast<const float4*>(wb + (size_t)k * SRC);
        float a0 = 0.f, a1 = 0.f, a2 = 0.f, a3 = 0.f;   // 4 indep chains
#pragma unroll
        for (int q = 0; q < PC / 4; ++q) {
            float4 w = wk[q];                     // wave-uniform -> scalar/bcast
            a0 += w.x * f[q * 4 + 0];
            a1 += w.y * f[q * 4 + 1];
            a2 += w.z * f[q * 4 + 2];
            a3 += w.w * f[q * 4 + 3];
        }
        op[(size_t)k * CC] = (a0 + a1) + (a2 + a3);     // coalesced store
    }
}

// ---- Phase 3: reduce s-partials, normalize, batch-mean ----------------------
__global__ __launch_bounds__(256)
void p3_finalize(const float* __restrict__ partial,  // [B][NS][K][C]
                 const float* __restrict__ counts,
                 float* __restrict__ out)            // [K][C], pre-zeroed
{
    int k = blockIdx.x, b = blockIdx.y;
    int c = threadIdx.x;
    const float* base = partial + ((size_t)(b * NS) * KC + k) * CC + c;
    float acc = 0.f;
#pragma unroll 4
    for (int s = 0; s < NS; ++s) acc += base[(size_t)s * KC * CC];
    float denom = 8.0f * (counts[b * KC + k] + 1e-6f);
    atomicAdd(&out[k * CC + c], acc / denom);
}

extern "C" void kernel_launch(void* const* d_in, const int* in_sizes, int n_in,
                              void* d_out, int out_size, void* d_ws, size_t ws_size,
                              hipStream_t stream) {
    const float* feats = (const float*)d_in[0];   // [8,256,64,64]
    const float* preds = (const float*)d_in[1];   // [8,21,256,256]
    const int*   masks = (const int*)  d_in[2];   // [8,256,256]
    float* out = (float*)d_out;                   // [21,256]

    float* ws      = (float*)d_ws;
    float* counts  = ws + WS_COUNTS;
    float* Wmap    = ws + WS_WMAP;
    float* partial = ws + WS_PART;

    hipMemsetAsync(out, 0, (size_t)KC * CC * sizeof(float), stream);
    p0_zero<<<(WS_ZERO / 4 + 255) / 256, 256, 0, stream>>>(ws);
    p1_classify_scatter<<<(BB * HWP / 4) / 256, 256, 0, stream>>>(preds, masks, Wmap, counts);
    p2_contract<<<dim3(NS, BB), 256, 0, stream>>>(feats, Wmap, partial);
    p3_finalize<<<dim3(KC, BB), 256, 0, stream>>>(partial, counts, out);
}

// Round 8
// 38.836 us; speedup vs baseline: 1.4524x; 1.4524x over previous
//
#include <hip/hip_runtime.h>

#define KC   21      // num classes
#define BB   8       // batch
#define CC   256     // feat channels
#define HWP  65536   // 256*256 output pixels per image
#define SRC  4096    // 64*64 source pixels
#define NS   128     // chunks: (y-row, half) -> 32 source cells each
#define PC   32      // source cells per chunk
#define FST  257     // fs row stride: bank=(p+c)%32 -> <=2-way (free)

// d_ws float layout: L bytes [0,131072) | partialw [131072,+21504) | partial [152576,+5505024)
#define WSF_PARTW 131072
#define WSF_PART  (WSF_PARTW + BB*NS*KC)     // 152576

// ---- k1: per-pixel argmax + gt-match -> label map L (255 = no match) --------
// Also zeroes out[21*256] (block 0). No atomics, fully deterministic.
__global__ __launch_bounds__(256)
void k1_classify(const float* __restrict__ preds,
                 const int*   __restrict__ masks,
                 unsigned char* __restrict__ L,
                 float* __restrict__ out)
{
    int tid = threadIdx.x;
    if (blockIdx.x == 0) {
        float4* o4 = reinterpret_cast<float4*>(out);
#pragma unroll
        for (int i = 0; i < (KC * CC / 4 + 255) / 256; ++i) {
            int j = tid + i * 256;
            if (j < KC * CC / 4) o4[j] = make_float4(0.f, 0.f, 0.f, 0.f);
        }
    }

    int idx = blockIdx.x * 256 + tid;            // over B*HWP/4 = 131072
    int b   = idx >> 14;
    int hw4 = (idx & 16383) << 2;

    const float* pb = preds + (size_t)b * KC * HWP + hw4;
    float4 v[KC];
#pragma unroll
    for (int k = 0; k < KC; ++k)
        v[k] = *reinterpret_cast<const float4*>(pb + (size_t)k * HWP);

    int4 mm = *reinterpret_cast<const int4*>(masks + b * HWP + hw4);

    float bx = v[0].x, by = v[0].y, bz = v[0].z, bw = v[0].w;
    int   ix = 0, iy = 0, iz = 0, iw = 0;
#pragma unroll
    for (int k = 1; k < KC; ++k) {
        if (v[k].x > bx) { bx = v[k].x; ix = k; }   // strict >: first-index tie rule
        if (v[k].y > by) { by = v[k].y; iy = k; }
        if (v[k].z > bz) { bz = v[k].z; iz = k; }
        if (v[k].w > bw) { bw = v[k].w; iw = k; }
    }

    uchar4 r;
    r.x = (mm.x == ix) ? (unsigned char)ix : (unsigned char)255;
    r.y = (mm.y == iy) ? (unsigned char)iy : (unsigned char)255;
    r.z = (mm.z == iz) ? (unsigned char)iz : (unsigned char)255;
    r.w = (mm.w == iw) ? (unsigned char)iw : (unsigned char)255;
    *reinterpret_cast<uchar4*>(L + (size_t)b * HWP + hw4) = r;
}

// ---- k2: per-chunk local W gather + contraction ------------------------------
// Block (s,b): owns 32 source cells (row y = s>>1, cols x0c..x0c+31).
// Builds ws[21][32] in LDS by gathering labels over the 8x136 influence zone
// (LDS atomics on exact dyadic weights -> order-independent, bit-exact).
// Then partial[b,s,k,c] = sum_p feats[b,c,p]*ws[k,p] (plain stores), and
// partialw[b,s,k] = row-sum of ws (exact count contribution).
__global__ __launch_bounds__(256, 4)
void k2_contract(const float* __restrict__ feats,      // [B][C][SRC]
                 const unsigned char* __restrict__ L,  // [B][256][256]
                 float* __restrict__ partial,          // [B][NS][K][C]
                 float* __restrict__ partialw)         // [B][NS][K]
{
    __shared__ float fs[PC * FST];    // [32 p][257] = 32.9 KB
    __shared__ float ws[KC * PC];     // [21][32]   =  2.6 KB  (35.6 KB -> 4/CU)
    int s = blockIdx.x, b = blockIdx.y;
    int tid = threadIdx.x;
    int y = s >> 1, x0c = (s & 1) * PC;
    int p0 = y * 64 + x0c;

    if (tid < KC * PC / 4)
        *reinterpret_cast<float4*>(ws + tid * 4) = make_float4(0.f, 0.f, 0.f, 0.f);
    __syncthreads();

    // stage feats[256 c][32 p] transposed -> fs[p][c]; 8 float4/thread
    {
        int q = tid & 7, c0 = tid >> 3;
#pragma unroll
        for (int i = 0; i < 8; ++i) {
            int c = i * 32 + c0;
            float4 f4 = *reinterpret_cast<const float4*>(
                feats + (size_t)(b * CC + c) * SRC + p0 + q * 4);
            fs[(q * 4 + 0) * FST + c] = f4.x;
            fs[(q * 4 + 1) * FST + c] = f4.y;
            fs[(q * 4 + 2) * FST + c] = f4.z;
            fs[(q * 4 + 3) * FST + c] = f4.w;
        }
    }

    // gather labels over influence zone: rows h in [4y-2, 4y+5], cols w in [4x0c-2, 4x0c+133]
    {
        int r = tid >> 5, cb = tid & 31;
        int h = 4 * y - 2 + r;
        if ((unsigned)h < 256u) {
            float sy = h * 0.25f - 0.375f;
            int   yt = (int)floorf(sy);
            float wy = sy - (float)yt;
            int ya = yt < 0 ? 0 : yt;
            int yb = yt + 1 > 63 ? 63 : yt + 1;
            float wyy = ((ya == y) ? (1.f - wy) : 0.f) + ((yb == y) ? wy : 0.f);
            if (wyy != 0.f) {
                const unsigned char* Lrow = L + ((size_t)b << 16) + ((size_t)h << 8);
                int wb0 = 4 * x0c - 2;
#pragma unroll
                for (int j = 0; j < 5; ++j) {
                    int col = cb + j * 32;
                    int w = wb0 + col;
                    if (col < 136 && (unsigned)w < 256u) {
                        int k = Lrow[w];
                        if (k < KC) {
                            float sx = w * 0.25f - 0.375f;
                            int   xt = (int)floorf(sx);
                            float wx = sx - (float)xt;
                            int xa = xt < 0 ? 0 : xt;
                            int xb = xt + 1 > 63 ? 63 : xt + 1;
                            if (xa >= x0c && xa < x0c + PC)
                                atomicAdd(&ws[k * PC + xa - x0c], wyy * (1.f - wx));
                            if (xb >= x0c && xb < x0c + PC)
                                atomicAdd(&ws[k * PC + xb - x0c], wyy * wx);
                        }
                    }
                }
            }
        }
    }
    __syncthreads();

    // pull own channel column into registers
    float f[PC];
#pragma unroll
    for (int p = 0; p < PC; ++p) f[p] = fs[p * FST + tid];

    float* op = partial + ((size_t)(b * NS + s)) * KC * CC + tid;
#pragma unroll 3
    for (int k = 0; k < KC; ++k) {
        const float* wk = ws + k * PC;
        float a0 = 0.f, a1 = 0.f, a2 = 0.f, a3 = 0.f;
#pragma unroll
        for (int q = 0; q < PC / 4; ++q) {
            float4 w4 = *reinterpret_cast<const float4*>(wk + q * 4);  // LDS bcast
            a0 += w4.x * f[q * 4 + 0];
            a1 += w4.y * f[q * 4 + 1];
            a2 += w4.z * f[q * 4 + 2];
            a3 += w4.w * f[q * 4 + 3];
        }
        op[(size_t)k * CC] = (a0 + a1) + (a2 + a3);   // coalesced store
    }

    // exact per-chunk class-count contribution (rotated reads: bank (p+tid)%32)
    if (tid < KC) {
        float sw = 0.f;
#pragma unroll
        for (int p = 0; p < PC; ++p) sw += ws[tid * PC + ((p + tid) & (PC - 1))];
        partialw[(size_t)(b * NS + s) * KC + tid] = sw;  // dyadic-exact
    }
}

// ---- k3: reduce chunks, derive exact counts, normalize, batch-mean ----------
__global__ __launch_bounds__(256)
void k3_finalize(const float* __restrict__ partial,   // [B][NS][K][C]
                 const float* __restrict__ partialw,  // [B][NS][K]
                 float* __restrict__ out)             // [K][C], zeroed by k1
{
    int k = blockIdx.x, b = blockIdx.y;
    int tid = threadIdx.x;

    const float* base = partial + ((size_t)(b * NS) * KC + k) * CC + tid;
    float acc = 0.f;
#pragma unroll 8
    for (int s = 0; s < NS; ++s) acc += base[(size_t)s * KC * CC];

    __shared__ float red[2];
    float v = 0.f;
    if (tid < NS) v = partialw[(size_t)(b * NS + tid) * KC + k];
#pragma unroll
    for (int off = 32; off; off >>= 1) v += __shfl_down(v, off);
    if (tid < NS && (tid & 63) == 0) red[tid >> 6] = v;
    __syncthreads();
    float cnt = red[0] + red[1];     // dyadic-exact pixel count

    atomicAdd(&out[k * CC + tid], acc / (8.f * (cnt + 1e-6f)));
}

extern "C" void kernel_launch(void* const* d_in, const int* in_sizes, int n_in,
                              void* d_out, int out_size, void* d_ws, size_t ws_size,
                              hipStream_t stream) {
    const float* feats = (const float*)d_in[0];   // [8,256,64,64]
    const float* preds = (const float*)d_in[1];   // [8,21,256,256]
    const int*   masks = (const int*)  d_in[2];   // [8,256,256]
    float* out = (float*)d_out;                   // [21,256]

    float* wsf = (float*)d_ws;
    unsigned char* L = (unsigned char*)d_ws;      // 512 KB, fully overwritten by k1
    float* partialw = wsf + WSF_PARTW;
    float* partial  = wsf + WSF_PART;

    k1_classify<<<(BB * HWP / 4) / 256, 256, 0, stream>>>(preds, masks, L, out);
    k2_contract<<<dim3(NS, BB), 256, 0, stream>>>(feats, L, partial, partialw);
    k3_finalize<<<dim3(KC, BB), 256, 0, stream>>>(partial, partialw, out);
}